// Round 12
// baseline (573.703 us; speedup 1.0000x reference)
//
#include <hip/hip_runtime.h>
#include <hip/hip_bf16.h>

// FiLM block, MI355X. I/O fp32; compute bf16 MFMA, fp32 accum.
// R18 = R17 with the launch-grid bug fixed. R17's core dump was NOT the
// kernel body: the launch line said O_CH*(NTOK/2048)*8 = 2048 blocks (stale
// *8 from the 512-block decode) while the kernel decodes q=bid>>7 assuming
// bid<256 -> tok0 up to 260096 >> NTOK -> OOB x reads / out writes -> abort.
// Grid is now 256. Kernel body byte-identical to R17 (hand-off algebra
// re-audited: m'=ks>>1, g'=2(ks&1)+u_dest for local / +1-u for send, word
// placement u'=0 -> w0,w1 / u'=1 -> w2,w3, L2 f=(reg&3)+8*(reg>>2)+4u).
//
// R17 design (vs R16, passed 69us, LDS-bound):
//  - mfma_f32_32x32x16_bf16: same 16B/lane A-read feeds 2x the MACs ->
//    A-read LDS traffic per FLOP halved. C/D layout HW-verified (m74/m101):
//    col=lane&31, row=(reg&3)+8*(reg>>2)+4*(lane>>5). A/B canonical:
//    row/col=lane&31, k=8*(lane>>5)+j.
//  - Token col = lane&31 in BOTH C and B layouts -> inter-layer hand-off is
//    a 2-lane exchange (l <-> l^32): shfl_xor(.,32) + cndmask selects.
//    SH h-scratch DELETED (no LDS round-trip, no SH bank conflicts).
//  - W2 zero-padded to 32 rows so L2 runs the same 32x32 path.
//  - LDS 65.1KB; 16 waves x 32 tok x 4 mt = 2048 tok/block; 256 blocks;
//    4 waves/SIMD, 128-VGPR budget via waves_per_eu(4,4).
// Staging (fused prep) and XCD swizzle: R16 verbatim (bid = q*128+o*8+c).
#define NTOK  32768
#define CIN   64
#define HDIM  128
#define O_CH  16
#define F2    16
#define MT    4
#define SLOPE 0.01f
#define EPS   1e-5f

// LDS layout (shorts). Weight rows 16B-aligned.
#define SW0_STRIDE 72
#define SW1_STRIDE 136
#define SW2_STRIDE 136
#define SW0_OFF 0                         // 128 x 72  = 9216
#define SW1_OFF 9216                      // 128 x 136 = 17408
#define SW2_OFF (9216 + 17408)            // 32  x 136 = 4352 (rows 16+ zero)
#define SBIAS_OFF (SW2_OFF + 32 * SW2_STRIDE)       // 30976; 4B-aligned
#define SBIAS_FLOATS 272                  // b0'(128) b1'(128) b2'(16)
#define SGB_OFF (SBIAS_OFF + SBIAS_FLOATS * 2)      // 31520
#define SGB_FLOATS 512                    // g0,be0,g1,be1
#define SMEM_SHORTS (SGB_OFF + SGB_FLOATS * 2)      // 32544 sh = 65088 B

typedef __attribute__((ext_vector_type(8)))  short bf16x8;
typedef __attribute__((ext_vector_type(4)))  float f32x4;
typedef __attribute__((ext_vector_type(16))) float f32x16;
typedef __attribute__((ext_vector_type(2)))  float f32x2;

__device__ __forceinline__ unsigned short f2b(float f) {
  union { float f; unsigned int i; } v;
  v.f = f;
  unsigned int i = v.i;
  unsigned int r = (i + 0x7fffu + ((i >> 16) & 1u)) >> 16;  // RNE
  return (unsigned short)r;
}
// native float->bf16 (RNE). [validated R10/R12/R13]
__device__ __forceinline__ unsigned short f2bn(float f) {
  union { __hip_bfloat16 h; unsigned short s; } v;
  v.h = __float2bfloat16(f);
  return v.s;
}
__device__ __forceinline__ unsigned pku(float lo, float hi) {
  return (unsigned)f2bn(lo) | ((unsigned)f2bn(hi) << 16);
}
__device__ __forceinline__ float leaky(float t) {
  return fmaxf(t, SLOPE * t);   // == LeakyReLU for all finite t
}
__device__ __forceinline__ f32x2 leaky2(f32x2 t) {
#if __has_builtin(__builtin_elementwise_max) && __has_builtin(__builtin_elementwise_min)
  f32x2 z = {0.f, 0.f};
  f32x2 pos = __builtin_elementwise_max(t, z);
  f32x2 neg = __builtin_elementwise_min(t, z);
  return pos + SLOPE * neg;
#else
  f32x2 r;
  r.x = fmaxf(t.x, SLOPE * t.x);
  r.y = fmaxf(t.y, SLOPE * t.y);
  return r;
#endif
}
__device__ __forceinline__ bf16x8 cvt8(const float* __restrict__ p) {
  float4 a = *(const float4*)p;
  float4 b = *(const float4*)(p + 4);
  bf16x8 r;
  r[0] = (short)f2b(a.x); r[1] = (short)f2b(a.y);
  r[2] = (short)f2b(a.z); r[3] = (short)f2b(a.w);
  r[4] = (short)f2b(b.x); r[5] = (short)f2b(b.y);
  r[6] = (short)f2b(b.z); r[7] = (short)f2b(b.w);
  return r;
}
__device__ __forceinline__ bf16x8 cvt8s(const float* __restrict__ p,
                                        const float* __restrict__ s) {
  bf16x8 r;
#pragma unroll
  for (int i = 0; i < 8; ++i) r[i] = (short)f2b(p[i] * s[i]);
  return r;
}

// Hand-off state: packed bf16 pairs of the lane's normalized h-values,
// pre-selected (compile-time indices only) for local/send use per ks parity.
struct Hx {
  unsigned Le01[4], Le23[4], Lo01[4], Lo23[4];
  unsigned Se01[4], Se23[4], So01[4], So23[4];
};

// leaky + LayerNorm on 32x32 C-layout. Lane (t=l&31,u=l>>5) holds
// h = 32m+8g+4u+i (m,g=0..3,i=0..3) of token t; lane pair (l,l^32) holds
// all 128. Stats: in-lane 64-sum (f32x2 chains) + ONE shfl_xor(32).
// Pack p01/p23[g] per m, then u-select into Le/Lo (local g=u,2+u) and
// Se/So (send g=1-u,3-u).
__device__ __forceinline__ void leaky_ln_hand(f32x16* acc, int u, Hx& h) {
  f32x2 sa = {0.f, 0.f}, sb = {0.f, 0.f};
  f32x2 qa = {0.f, 0.f}, qb = {0.f, 0.f};
#pragma unroll
  for (int m = 0; m < 4; ++m) {
#pragma unroll
    for (int g = 0; g < 4; ++g) {
      f32x2 t0 = {acc[m][4 * g + 0], acc[m][4 * g + 1]};
      f32x2 t1 = {acc[m][4 * g + 2], acc[m][4 * g + 3]};
      t0 = leaky2(t0);
      t1 = leaky2(t1);
      acc[m][4 * g + 0] = t0.x; acc[m][4 * g + 1] = t0.y;
      acc[m][4 * g + 2] = t1.x; acc[m][4 * g + 3] = t1.y;
      sa += t0; sb += t1;
      qa += t0 * t0; qb += t1 * t1;
    }
  }
  float s1 = (sa.x + sa.y) + (sb.x + sb.y);
  float s2 = (qa.x + qa.y) + (qb.x + qb.y);
  s1 += __shfl_xor(s1, 32);
  s2 += __shfl_xor(s2, 32);
  float mu = s1 * (1.0f / 128.0f);
  float var = s2 * (1.0f / 128.0f) - mu * mu;
  float rs = rsqrtf(var + EPS);
  float nm = -mu * rs;
#pragma unroll
  for (int m = 0; m < 4; ++m) {
    unsigned p01[4], p23[4];
#pragma unroll
    for (int g = 0; g < 4; ++g) {
      float y0 = fmaf(acc[m][4 * g + 0], rs, nm);
      float y1 = fmaf(acc[m][4 * g + 1], rs, nm);
      float y2 = fmaf(acc[m][4 * g + 2], rs, nm);
      float y3 = fmaf(acc[m][4 * g + 3], rs, nm);
      p01[g] = pku(y0, y1);
      p23[g] = pku(y2, y3);
    }
    h.Le01[m] = u ? p01[1] : p01[0];  h.Le23[m] = u ? p23[1] : p23[0];
    h.Lo01[m] = u ? p01[3] : p01[2];  h.Lo23[m] = u ? p23[3] : p23[2];
    h.Se01[m] = u ? p01[0] : p01[1];  h.Se23[m] = u ? p23[0] : p23[1];
    h.So01[m] = u ? p01[2] : p01[3];  h.So23[m] = u ? p23[2] : p23[3];
  }
}

// B-fragment for k-step ks (K=16 each): words 0,1 from the u'=0 owner
// (lane t), words 2,3 from u'=1 (lane t+32). ks compile-time via unroll.
__device__ __forceinline__ bf16x8 build_b(const Hx& h, int ks, int u) {
  const int m = ks >> 1;
  unsigned sA, sB, lA, lB;
  if (ks & 1) { sA = h.So01[m]; sB = h.So23[m]; lA = h.Lo01[m]; lB = h.Lo23[m]; }
  else        { sA = h.Se01[m]; sB = h.Se23[m]; lA = h.Le01[m]; lB = h.Le23[m]; }
  unsigned rA = __shfl_xor(sA, 32);
  unsigned rB = __shfl_xor(sB, 32);
  union { unsigned w[4]; bf16x8 v; } b;
  b.w[0] = u ? rA : lA;  b.w[1] = u ? rB : lB;
  b.w[2] = u ? lA : rA;  b.w[3] = u ? lB : rB;
  return b.v;
}

// film_main: block = one o x 2048 tokens (16 waves x 4 mt x 32 tokens).
// LDS 65.1KB (weights zero-padded W2 + biases); 4 waves/SIMD, budget 128
// VGPR via waves_per_eu(4,4). No in-loop barriers (no shared scratch).
__global__ __launch_bounds__(1024)
__attribute__((amdgpu_waves_per_eu(4, 4))) void film_main(
    const float* __restrict__ x,
    const float* __restrict__ W0, const float* __restrict__ b0,
    const float* __restrict__ g0, const float* __restrict__ be0,
    const float* __restrict__ W1, const float* __restrict__ b1,
    const float* __restrict__ g1, const float* __restrict__ be1,
    const float* __restrict__ W2, const float* __restrict__ b2,
    float* __restrict__ out) {
  __shared__ unsigned short smem[SMEM_SHORTS];
  const int tid = threadIdx.x;
  const int c   = blockIdx.x & 7;
  const int o   = (blockIdx.x >> 3) & 15;
  const int q   = blockIdx.x >> 7;              // 0..1
  const int tok0 = (q * 8 + c) * 2048;

  float* sbias = (float*)&smem[SBIAS_OFF];
  float* sgb   = (float*)&smem[SGB_OFF];
  float* sg0v  = sgb;
  float* sbe0v = sgb + 128;
  float* sg1v  = sgb + 256;
  float* sbe1v = sgb + 384;

  // ---- staging 1: gamma/beta fp32 into LDS [R16]
  if (tid < 128)      sg0v [tid]       = g0 [o * HDIM + tid];
  else if (tid < 256) sbe0v[tid - 128] = be0[o * HDIM + (tid - 128)];
  else if (tid < 384) sg1v [tid - 256] = g1 [o * HDIM + (tid - 256)];
  else if (tid < 512) sbe1v[tid - 384] = be1[o * HDIM + (tid - 384)];
  __syncthreads();

  // ---- staging 2: weight image + folded biases [R16 + W2 zero-pad]
  const float* w0 = W0 + (size_t)o * HDIM * CIN;
  const float* w1 = W1 + (size_t)o * HDIM * HDIM;
  const float* w2 = W2 + (size_t)o * F2 * HDIM;
  {  // W0: 1024 chunks of 8
    int cc = tid, n = cc >> 3, k8 = cc & 7;
    *(bf16x8*)&smem[SW0_OFF + n * SW0_STRIDE + k8 * 8] = cvt8(w0 + cc * 8);
  }
#pragma unroll
  for (int rep = 0; rep < 2; ++rep) {  // W1: 2048 chunks
    int cc = tid + rep * 1024, n = cc >> 4, k8 = cc & 15;
    *(bf16x8*)&smem[SW1_OFF + n * SW1_STRIDE + k8 * 8] =
        cvt8s(w1 + cc * 8, sg0v + k8 * 8);         // W1' = W1 * g0[k]
  }
  if (tid < 512) {  // W2 padded to 32 rows: rows 16..31 zero
    int cc = tid, n = cc >> 4, k8 = cc & 15;
    bf16x8 v;
    if (n < 16) {
      v = cvt8s(w2 + (n * HDIM + k8 * 8), sg1v + k8 * 8);  // W2' = W2 * g1
    } else {
#pragma unroll
      for (int i = 0; i < 8; ++i) v[i] = 0;
    }
    *(bf16x8*)&smem[SW2_OFF + n * SW2_STRIDE + k8 * 8] = v;
  }
  if (tid < 128) sbias[tid] = b0[o * HDIM + tid];  // b0' = b0
  {  // b1' = b1 + W1*be0 : 8 threads per h-row [R16]
    int hrow = tid >> 3, seg = tid & 7;
    const float* w1r = w1 + (size_t)hrow * HDIM + seg * 16;
    const float* bev = sbe0v + seg * 16;
    float p = 0.f;
#pragma unroll
    for (int k = 0; k < 16; ++k) p = fmaf(w1r[k], bev[k], p);
    p += __shfl_xor(p, 1); p += __shfl_xor(p, 2); p += __shfl_xor(p, 4);
    if (seg == 0) sbias[HDIM + hrow] = b1[o * HDIM + hrow] + p;
  }
  if (tid < 128) {  // b2' = b2 + W2*be1 : 8 threads per f-row [R16]
    int f = tid >> 3, seg = tid & 7;
    const float* w2r = w2 + (size_t)f * HDIM + seg * 16;
    const float* bev = sbe1v + seg * 16;
    float p = 0.f;
#pragma unroll
    for (int k = 0; k < 16; ++k) p = fmaf(w2r[k], bev[k], p);
    p += __shfl_xor(p, 1); p += __shfl_xor(p, 2); p += __shfl_xor(p, 4);
    if (seg == 0) sbias[2 * HDIM + f] = b2[o * F2 + f] + p;
  }

  const int lane = tid & 63;
  const int wave = tid >> 6;        // 0..15
  const int t32  = lane & 31;       // token column (C and B layouts)
  const int u    = lane >> 5;       // lane-half
  const float* sb0 = sbias;
  const float* sb1 = sbias + HDIM;
  const float* sb2 = sbias + 2 * HDIM;
  __syncthreads();

  // per-lane L2 bias fragment (f = 4u + (reg&3) + 8*(reg>>2), reg 0..7)
  const f32x4 b2ra = *(const f32x4*)(sb2 + 4 * u);      // regs 0..3
  const f32x4 b2rb = *(const f32x4*)(sb2 + 8 + 4 * u);  // regs 4..7

  // hoisted LDS byte bases (A-reads: row = t32 (+32m), k-offset 8u)
  const unsigned short* a0p = &smem[SW0_OFF + t32 * SW0_STRIDE + 8 * u];
  const unsigned short* a1p = &smem[SW1_OFF + t32 * SW1_STRIDE + 8 * u];
  const unsigned short* a2p = &smem[SW2_OFF + t32 * SW2_STRIDE + 8 * u];

  const int tbase = tok0 + wave * (32 * MT);

  for (int mt = 0; mt < MT; ++mt) {
    const int trow = tbase + mt * 32;
    const float* xr = x + (size_t)(trow + t32) * CIN + 8 * u;

    // ---- Layer 0: A=W0 (LDS), B=x (global, fp32 -> bf16 native cvt)
    f32x16 acc[4];
#pragma unroll
    for (int m = 0; m < 4; ++m)
#pragma unroll
      for (int g = 0; g < 4; ++g) {
        f32x4 bv = *(const f32x4*)(sb0 + 32 * m + 8 * g + 4 * u);
#pragma unroll
        for (int i = 0; i < 4; ++i) acc[m][4 * g + i] = bv[i];
      }
#pragma unroll
    for (int ks = 0; ks < 4; ++ks) {
      float4 xa = *(const float4*)(xr + 16 * ks);
      float4 xb = *(const float4*)(xr + 16 * ks + 4);
      bf16x8 bx;
      bx[0] = (short)f2bn(xa.x); bx[1] = (short)f2bn(xa.y);
      bx[2] = (short)f2bn(xa.z); bx[3] = (short)f2bn(xa.w);
      bx[4] = (short)f2bn(xb.x); bx[5] = (short)f2bn(xb.y);
      bx[6] = (short)f2bn(xb.z); bx[7] = (short)f2bn(xb.w);
#pragma unroll
      for (int m = 0; m < 4; ++m) {
        bf16x8 a = *(const bf16x8*)(a0p + m * 32 * SW0_STRIDE + 16 * ks);
        acc[m] = __builtin_amdgcn_mfma_f32_32x32x16_bf16(a, bx, acc[m], 0, 0, 0);
      }
    }
    Hx hx;
    leaky_ln_hand(acc, u, hx);

    // ---- Layer 1: A=W1' (LDS), B=h0 via 2-lane register exchange
#pragma unroll
    for (int m = 0; m < 4; ++m)
#pragma unroll
      for (int g = 0; g < 4; ++g) {
        f32x4 bv = *(const f32x4*)(sb1 + 32 * m + 8 * g + 4 * u);
#pragma unroll
        for (int i = 0; i < 4; ++i) acc[m][4 * g + i] = bv[i];
      }
#pragma unroll
    for (int ks = 0; ks < 8; ++ks) {
      bf16x8 bh = build_b(hx, ks, u);
#pragma unroll
      for (int m = 0; m < 4; ++m) {
        bf16x8 a = *(const bf16x8*)(a1p + m * 32 * SW1_STRIDE + 16 * ks);
        acc[m] = __builtin_amdgcn_mfma_f32_32x32x16_bf16(a, bh, acc[m], 0, 0, 0);
      }
    }
    leaky_ln_hand(acc, u, hx);

    // ---- Layer 2: A=W2' (32-row zero-padded), B=h1
    f32x16 acc2;
#pragma unroll
    for (int i = 0; i < 4; ++i) acc2[i] = b2ra[i];
#pragma unroll
    for (int i = 0; i < 4; ++i) acc2[4 + i] = b2rb[i];
#pragma unroll
    for (int i = 8; i < 16; ++i) acc2[i] = 0.f;
#pragma unroll
    for (int ks = 0; ks < 8; ++ks) {
      bf16x8 bh = build_b(hx, ks, u);
      bf16x8 a = *(const bf16x8*)(a2p + 16 * ks);
      acc2 = __builtin_amdgcn_mfma_f32_32x32x16_bf16(a, bh, acc2, 0, 0, 0);
    }
    // out[tok][f][o]: f = 4u + (reg&3) + 8*(reg>>2), regs 0..7 only.
    {
      float* ob = out + (size_t)(trow + t32) * (F2 * O_CH) + 64 * u + o;
#pragma unroll
      for (int r = 0; r < 4; ++r) ob[16 * r]       = leaky(acc2[r]);
#pragma unroll
      for (int r = 0; r < 4; ++r) ob[16 * (8 + r)] = leaky(acc2[4 + r]);
    }
  }
}

extern "C" void kernel_launch(void* const* d_in, const int* in_sizes, int n_in,
                              void* d_out, int out_size, void* d_ws, size_t ws_size,
                              hipStream_t stream) {
  (void)in_sizes; (void)n_in; (void)out_size; (void)d_ws; (void)ws_size;
  const float* x   = (const float*)d_in[0];
  const float* W0  = (const float*)d_in[1];
  const float* b0  = (const float*)d_in[2];
  const float* g0  = (const float*)d_in[3];
  const float* be0 = (const float*)d_in[4];
  const float* W1  = (const float*)d_in[5];
  const float* b1  = (const float*)d_in[6];
  const float* g1  = (const float*)d_in[7];
  const float* be1 = (const float*)d_in[8];
  const float* W2  = (const float*)d_in[9];
  const float* b2  = (const float*)d_in[10];

  // 256 blocks: 16 o-channels x 16 token-groups of 2048. (R17 bug: *8.)
  film_main<<<dim3(O_CH * (NTOK / 2048)), dim3(1024), 0, stream>>>(
      x, W0, b0, g0, be0, W1, b1, g1, be1, W2, b2, (float*)d_out);
}

// Round 13
// 332.742 us; speedup vs baseline: 1.7242x; 1.7242x over previous
//
#include <hip/hip_runtime.h>
#include <hip/hip_bf16.h>

// FiLM block, MI355X. I/O fp32; compute bf16 MFMA, fp32 accum.
// R19 = R18's VALIDATED 32x32 kernel (passed, absmax 0.0156, bank-conflicts
// 10.1M -> 114K) moved from 1024-thread to 512-thread blocks.
// R18's 504us was pure VGPR spill (VGPR_Count=64, FETCH 796MB, WRITE 502MB):
// six data points show 1024-thread blocks are ALWAYS allocated 64 regs on
// this toolchain (bare/(1024,4)/waves_per_eu all ignored upward) while the
// 256-thread R0 kernel was granted 108. The 32x32 structure needs ~140.
// 512-thread blocks: flat size implies min 2 waves/SIMD -> budget 256 ->
// allocator grants demand -> NO SPILLS. LDS 65.1KB -> 2 blocks/CU; occupancy
// 4 waves/SIMD if alloc <=128, else 2 -- either way no spill catastrophe.
//
// Design (validated in R18): mfma_f32_32x32x16_bf16, token col = lane&31 in
// both C and B layouts -> inter-layer h hand-off is a 2-lane exchange
// (shfl_xor 32 + cndmask), SH deleted, W2 zero-padded to 32 rows, C/D
// row=(reg&3)+8*(reg>>2)+4*(lane>>5) [m74/m101]. No in-loop barriers.
// Block = one o x 1024 tokens (8 waves x 4 mt x 32 tok); grid 512;
// XCD swizzle bid = q*128 + o*8 + c (q=0..3), tok-group tg=q*8+c.
#define NTOK  32768
#define CIN   64
#define HDIM  128
#define O_CH  16
#define F2    16
#define MT    4
#define SLOPE 0.01f
#define EPS   1e-5f

// LDS layout (shorts). Weight rows 16B-aligned.
#define SW0_STRIDE 72
#define SW1_STRIDE 136
#define SW2_STRIDE 136
#define SW0_OFF 0                         // 128 x 72  = 9216
#define SW1_OFF 9216                      // 128 x 136 = 17408
#define SW2_OFF (9216 + 17408)            // 32  x 136 = 4352 (rows 16+ zero)
#define SBIAS_OFF (SW2_OFF + 32 * SW2_STRIDE)       // 30976; 4B-aligned
#define SBIAS_FLOATS 272                  // b0'(128) b1'(128) b2'(16)
#define SGB_OFF (SBIAS_OFF + SBIAS_FLOATS * 2)      // 31520
#define SGB_FLOATS 512                    // g0,be0,g1,be1
#define SMEM_SHORTS (SGB_OFF + SGB_FLOATS * 2)      // 32544 sh = 65088 B

typedef __attribute__((ext_vector_type(8)))  short bf16x8;
typedef __attribute__((ext_vector_type(4)))  float f32x4;
typedef __attribute__((ext_vector_type(16))) float f32x16;
typedef __attribute__((ext_vector_type(2)))  float f32x2;

__device__ __forceinline__ unsigned short f2b(float f) {
  union { float f; unsigned int i; } v;
  v.f = f;
  unsigned int i = v.i;
  unsigned int r = (i + 0x7fffu + ((i >> 16) & 1u)) >> 16;  // RNE
  return (unsigned short)r;
}
// native float->bf16 (RNE). [validated R10/R12/R13]
__device__ __forceinline__ unsigned short f2bn(float f) {
  union { __hip_bfloat16 h; unsigned short s; } v;
  v.h = __float2bfloat16(f);
  return v.s;
}
__device__ __forceinline__ unsigned pku(float lo, float hi) {
  return (unsigned)f2bn(lo) | ((unsigned)f2bn(hi) << 16);
}
__device__ __forceinline__ float leaky(float t) {
  return fmaxf(t, SLOPE * t);   // == LeakyReLU for all finite t
}
__device__ __forceinline__ f32x2 leaky2(f32x2 t) {
#if __has_builtin(__builtin_elementwise_max) && __has_builtin(__builtin_elementwise_min)
  f32x2 z = {0.f, 0.f};
  f32x2 pos = __builtin_elementwise_max(t, z);
  f32x2 neg = __builtin_elementwise_min(t, z);
  return pos + SLOPE * neg;
#else
  f32x2 r;
  r.x = fmaxf(t.x, SLOPE * t.x);
  r.y = fmaxf(t.y, SLOPE * t.y);
  return r;
#endif
}
__device__ __forceinline__ bf16x8 cvt8(const float* __restrict__ p) {
  float4 a = *(const float4*)p;
  float4 b = *(const float4*)(p + 4);
  bf16x8 r;
  r[0] = (short)f2b(a.x); r[1] = (short)f2b(a.y);
  r[2] = (short)f2b(a.z); r[3] = (short)f2b(a.w);
  r[4] = (short)f2b(b.x); r[5] = (short)f2b(b.y);
  r[6] = (short)f2b(b.z); r[7] = (short)f2b(b.w);
  return r;
}
__device__ __forceinline__ bf16x8 cvt8s(const float* __restrict__ p,
                                        const float* __restrict__ s) {
  bf16x8 r;
#pragma unroll
  for (int i = 0; i < 8; ++i) r[i] = (short)f2b(p[i] * s[i]);
  return r;
}

// Hand-off state: packed bf16 pairs of the lane's normalized h-values,
// pre-selected (compile-time indices only) for local/send use per ks parity.
struct Hx {
  unsigned Le01[4], Le23[4], Lo01[4], Lo23[4];
  unsigned Se01[4], Se23[4], So01[4], So23[4];
};

// leaky + LayerNorm on 32x32 C-layout. Lane (t=l&31,u=l>>5) holds
// h = 32m+8g+4u+i (m,g=0..3,i=0..3) of token t; lane pair (l,l^32) holds
// all 128. Stats: in-lane 64-sum (f32x2 chains) + ONE shfl_xor(32).
// Pack p01/p23[g] per m, then u-select into Le/Lo (local g=u,2+u) and
// Se/So (send g=1-u,3-u).  [validated R18]
__device__ __forceinline__ void leaky_ln_hand(f32x16* acc, int u, Hx& h) {
  f32x2 sa = {0.f, 0.f}, sb = {0.f, 0.f};
  f32x2 qa = {0.f, 0.f}, qb = {0.f, 0.f};
#pragma unroll
  for (int m = 0; m < 4; ++m) {
#pragma unroll
    for (int g = 0; g < 4; ++g) {
      f32x2 t0 = {acc[m][4 * g + 0], acc[m][4 * g + 1]};
      f32x2 t1 = {acc[m][4 * g + 2], acc[m][4 * g + 3]};
      t0 = leaky2(t0);
      t1 = leaky2(t1);
      acc[m][4 * g + 0] = t0.x; acc[m][4 * g + 1] = t0.y;
      acc[m][4 * g + 2] = t1.x; acc[m][4 * g + 3] = t1.y;
      sa += t0; sb += t1;
      qa += t0 * t0; qb += t1 * t1;
    }
  }
  float s1 = (sa.x + sa.y) + (sb.x + sb.y);
  float s2 = (qa.x + qa.y) + (qb.x + qb.y);
  s1 += __shfl_xor(s1, 32);
  s2 += __shfl_xor(s2, 32);
  float mu = s1 * (1.0f / 128.0f);
  float var = s2 * (1.0f / 128.0f) - mu * mu;
  float rs = rsqrtf(var + EPS);
  float nm = -mu * rs;
#pragma unroll
  for (int m = 0; m < 4; ++m) {
    unsigned p01[4], p23[4];
#pragma unroll
    for (int g = 0; g < 4; ++g) {
      float y0 = fmaf(acc[m][4 * g + 0], rs, nm);
      float y1 = fmaf(acc[m][4 * g + 1], rs, nm);
      float y2 = fmaf(acc[m][4 * g + 2], rs, nm);
      float y3 = fmaf(acc[m][4 * g + 3], rs, nm);
      p01[g] = pku(y0, y1);
      p23[g] = pku(y2, y3);
    }
    h.Le01[m] = u ? p01[1] : p01[0];  h.Le23[m] = u ? p23[1] : p23[0];
    h.Lo01[m] = u ? p01[3] : p01[2];  h.Lo23[m] = u ? p23[3] : p23[2];
    h.Se01[m] = u ? p01[0] : p01[1];  h.Se23[m] = u ? p23[0] : p23[1];
    h.So01[m] = u ? p01[2] : p01[3];  h.So23[m] = u ? p23[2] : p23[3];
  }
}

// B-fragment for k-step ks (K=16 each): words 0,1 from the u'=0 owner
// (lane t), words 2,3 from u'=1 (lane t+32). ks compile-time via unroll.
// [validated R18]
__device__ __forceinline__ bf16x8 build_b(const Hx& h, int ks, int u) {
  const int m = ks >> 1;
  unsigned sA, sB, lA, lB;
  if (ks & 1) { sA = h.So01[m]; sB = h.So23[m]; lA = h.Lo01[m]; lB = h.Lo23[m]; }
  else        { sA = h.Se01[m]; sB = h.Se23[m]; lA = h.Le01[m]; lB = h.Le23[m]; }
  unsigned rA = __shfl_xor(sA, 32);
  unsigned rB = __shfl_xor(sB, 32);
  union { unsigned w[4]; bf16x8 v; } b;
  b.w[0] = u ? rA : lA;  b.w[1] = u ? rB : lB;
  b.w[2] = u ? lA : rA;  b.w[3] = u ? lB : rB;
  return b.v;
}

// film_main: 512-thread block = one o x 1024 tokens (8 waves x 4 mt x 32).
// LDS 65.1KB -> 2 blocks/CU. launch_bounds(512) only: flat size implies
// min 2 waves/SIMD -> VGPR budget 256 -> allocator grants demand (~140),
// no spills. No in-loop barriers (no shared scratch).
__global__ __launch_bounds__(512) void film_main(
    const float* __restrict__ x,
    const float* __restrict__ W0, const float* __restrict__ b0,
    const float* __restrict__ g0, const float* __restrict__ be0,
    const float* __restrict__ W1, const float* __restrict__ b1,
    const float* __restrict__ g1, const float* __restrict__ be1,
    const float* __restrict__ W2, const float* __restrict__ b2,
    float* __restrict__ out) {
  __shared__ unsigned short smem[SMEM_SHORTS];
  const int tid = threadIdx.x;
  const int c   = blockIdx.x & 7;
  const int o   = (blockIdx.x >> 3) & 15;
  const int q   = blockIdx.x >> 7;              // 0..3
  const int tok0 = (q * 8 + c) * 1024;

  float* sbias = (float*)&smem[SBIAS_OFF];
  float* sgb   = (float*)&smem[SGB_OFF];
  float* sg0v  = sgb;
  float* sbe0v = sgb + 128;
  float* sg1v  = sgb + 256;
  float* sbe1v = sgb + 384;

  // ---- staging 1: gamma/beta fp32 into LDS (512 threads cover 512 vals)
  if (tid < 128)      sg0v [tid]       = g0 [o * HDIM + tid];
  else if (tid < 256) sbe0v[tid - 128] = be0[o * HDIM + (tid - 128)];
  else if (tid < 384) sg1v [tid - 256] = g1 [o * HDIM + (tid - 256)];
  else                sbe1v[tid - 384] = be1[o * HDIM + (tid - 384)];
  __syncthreads();

  // ---- staging 2: weight image + folded biases (512-thread striding)
  const float* w0 = W0 + (size_t)o * HDIM * CIN;
  const float* w1 = W1 + (size_t)o * HDIM * HDIM;
  const float* w2 = W2 + (size_t)o * F2 * HDIM;
#pragma unroll
  for (int rep = 0; rep < 2; ++rep) {  // W0: 1024 chunks of 8
    int cc = tid + rep * 512, n = cc >> 3, k8 = cc & 7;
    *(bf16x8*)&smem[SW0_OFF + n * SW0_STRIDE + k8 * 8] = cvt8(w0 + cc * 8);
  }
#pragma unroll
  for (int rep = 0; rep < 4; ++rep) {  // W1: 2048 chunks
    int cc = tid + rep * 512, n = cc >> 4, k8 = cc & 15;
    *(bf16x8*)&smem[SW1_OFF + n * SW1_STRIDE + k8 * 8] =
        cvt8s(w1 + cc * 8, sg0v + k8 * 8);         // W1' = W1 * g0[k]
  }
  {  // W2 padded to 32 rows: rows 16..31 zero (512 chunks, one each)
    int cc = tid, n = cc >> 4, k8 = cc & 15;
    bf16x8 v;
    if (n < 16) {
      v = cvt8s(w2 + (n * HDIM + k8 * 8), sg1v + k8 * 8);  // W2' = W2 * g1
    } else {
#pragma unroll
      for (int i = 0; i < 8; ++i) v[i] = 0;
    }
    *(bf16x8*)&smem[SW2_OFF + n * SW2_STRIDE + k8 * 8] = v;
  }
  if (tid < 128) sbias[tid] = b0[o * HDIM + tid];  // b0' = b0
  {  // b1' = b1 + W1*be0 : 4 threads per h-row, 32-elem partials + reduce
    int hrow = tid >> 2, seg = tid & 3;
    const float* w1r = w1 + (size_t)hrow * HDIM + seg * 32;
    const float* bev = sbe0v + seg * 32;
    float p = 0.f;
#pragma unroll
    for (int k = 0; k < 32; ++k) p = fmaf(w1r[k], bev[k], p);
    p += __shfl_xor(p, 1); p += __shfl_xor(p, 2);
    if (seg == 0) sbias[HDIM + hrow] = b1[o * HDIM + hrow] + p;
  }
  if (tid < 128) {  // b2' = b2 + W2*be1 : 8 threads per f-row
    int f = tid >> 3, seg = tid & 7;
    const float* w2r = w2 + (size_t)f * HDIM + seg * 16;
    const float* bev = sbe1v + seg * 16;
    float p = 0.f;
#pragma unroll
    for (int k = 0; k < 16; ++k) p = fmaf(w2r[k], bev[k], p);
    p += __shfl_xor(p, 1); p += __shfl_xor(p, 2); p += __shfl_xor(p, 4);
    if (seg == 0) sbias[2 * HDIM + f] = b2[o * F2 + f] + p;
  }

  const int lane = tid & 63;
  const int wave = tid >> 6;        // 0..7
  const int t32  = lane & 31;       // token column (C and B layouts)
  const int u    = lane >> 5;       // lane-half
  const float* sb0 = sbias;
  const float* sb1 = sbias + HDIM;
  const float* sb2 = sbias + 2 * HDIM;
  __syncthreads();

  // per-lane L2 bias fragment (f = 4u + (reg&3) + 8*(reg>>2), reg 0..7)
  const f32x4 b2ra = *(const f32x4*)(sb2 + 4 * u);      // regs 0..3
  const f32x4 b2rb = *(const f32x4*)(sb2 + 8 + 4 * u);  // regs 4..7

  // hoisted LDS byte bases (A-reads: row = t32 (+32m), k-offset 8u)
  const unsigned short* a0p = &smem[SW0_OFF + t32 * SW0_STRIDE + 8 * u];
  const unsigned short* a1p = &smem[SW1_OFF + t32 * SW1_STRIDE + 8 * u];
  const unsigned short* a2p = &smem[SW2_OFF + t32 * SW2_STRIDE + 8 * u];

  const int tbase = tok0 + wave * (32 * MT);

  for (int mt = 0; mt < MT; ++mt) {
    const int trow = tbase + mt * 32;
    const float* xr = x + (size_t)(trow + t32) * CIN + 8 * u;

    // ---- Layer 0: A=W0 (LDS), B=x (global, fp32 -> bf16 native cvt)
    f32x16 acc[4];
#pragma unroll
    for (int m = 0; m < 4; ++m)
#pragma unroll
      for (int g = 0; g < 4; ++g) {
        f32x4 bv = *(const f32x4*)(sb0 + 32 * m + 8 * g + 4 * u);
#pragma unroll
        for (int i = 0; i < 4; ++i) acc[m][4 * g + i] = bv[i];
      }
#pragma unroll
    for (int ks = 0; ks < 4; ++ks) {
      float4 xa = *(const float4*)(xr + 16 * ks);
      float4 xb = *(const float4*)(xr + 16 * ks + 4);
      bf16x8 bx;
      bx[0] = (short)f2bn(xa.x); bx[1] = (short)f2bn(xa.y);
      bx[2] = (short)f2bn(xa.z); bx[3] = (short)f2bn(xa.w);
      bx[4] = (short)f2bn(xb.x); bx[5] = (short)f2bn(xb.y);
      bx[6] = (short)f2bn(xb.z); bx[7] = (short)f2bn(xb.w);
#pragma unroll
      for (int m = 0; m < 4; ++m) {
        bf16x8 a = *(const bf16x8*)(a0p + m * 32 * SW0_STRIDE + 16 * ks);
        acc[m] = __builtin_amdgcn_mfma_f32_32x32x16_bf16(a, bx, acc[m], 0, 0, 0);
      }
    }
    Hx hx;
    leaky_ln_hand(acc, u, hx);

    // ---- Layer 1: A=W1' (LDS), B=h0 via 2-lane register exchange
#pragma unroll
    for (int m = 0; m < 4; ++m)
#pragma unroll
      for (int g = 0; g < 4; ++g) {
        f32x4 bv = *(const f32x4*)(sb1 + 32 * m + 8 * g + 4 * u);
#pragma unroll
        for (int i = 0; i < 4; ++i) acc[m][4 * g + i] = bv[i];
      }
#pragma unroll
    for (int ks = 0; ks < 8; ++ks) {
      bf16x8 bh = build_b(hx, ks, u);
#pragma unroll
      for (int m = 0; m < 4; ++m) {
        bf16x8 a = *(const bf16x8*)(a1p + m * 32 * SW1_STRIDE + 16 * ks);
        acc[m] = __builtin_amdgcn_mfma_f32_32x32x16_bf16(a, bh, acc[m], 0, 0, 0);
      }
    }
    leaky_ln_hand(acc, u, hx);

    // ---- Layer 2: A=W2' (32-row zero-padded), B=h1
    f32x16 acc2;
#pragma unroll
    for (int i = 0; i < 4; ++i) acc2[i] = b2ra[i];
#pragma unroll
    for (int i = 0; i < 4; ++i) acc2[4 + i] = b2rb[i];
#pragma unroll
    for (int i = 8; i < 16; ++i) acc2[i] = 0.f;
#pragma unroll
    for (int ks = 0; ks < 8; ++ks) {
      bf16x8 bh = build_b(hx, ks, u);
      bf16x8 a = *(const bf16x8*)(a2p + 16 * ks);
      acc2 = __builtin_amdgcn_mfma_f32_32x32x16_bf16(a, bh, acc2, 0, 0, 0);
    }
    // out[tok][f][o]: f = 4u + (reg&3) + 8*(reg>>2), regs 0..7 only.
    {
      float* ob = out + (size_t)(trow + t32) * (F2 * O_CH) + 64 * u + o;
#pragma unroll
      for (int r = 0; r < 4; ++r) ob[16 * r]       = leaky(acc2[r]);
#pragma unroll
      for (int r = 0; r < 4; ++r) ob[16 * (8 + r)] = leaky(acc2[4 + r]);
    }
  }
}

extern "C" void kernel_launch(void* const* d_in, const int* in_sizes, int n_in,
                              void* d_out, int out_size, void* d_ws, size_t ws_size,
                              hipStream_t stream) {
  (void)in_sizes; (void)n_in; (void)out_size; (void)d_ws; (void)ws_size;
  const float* x   = (const float*)d_in[0];
  const float* W0  = (const float*)d_in[1];
  const float* b0  = (const float*)d_in[2];
  const float* g0  = (const float*)d_in[3];
  const float* be0 = (const float*)d_in[4];
  const float* W1  = (const float*)d_in[5];
  const float* b1  = (const float*)d_in[6];
  const float* g1  = (const float*)d_in[7];
  const float* be1 = (const float*)d_in[8];
  const float* W2  = (const float*)d_in[9];
  const float* b2  = (const float*)d_in[10];

  // 512 blocks: 16 o-channels x 32 token-groups of 1024.
  film_main<<<dim3(O_CH * (NTOK / 1024)), dim3(512), 0, stream>>>(
      x, W0, b0, g0, be0, W1, b1, g1, be1, W2, b2, (float*)d_out);
}

// Round 14
// 290.768 us; speedup vs baseline: 1.9731x; 1.1444x over previous
//
#include <hip/hip_runtime.h>
#include <hip/hip_bf16.h>

// FiLM block, MI355X. I/O fp32; compute bf16 MFMA, fp32 accum.
// R20 = R19 (validated 32x32, 512-thr blocks, VGPR=128 granted, but ~790MB
// spill traffic -> HBM-bound 266us) with register demand shaved below 128:
//  (1) #pragma unroll 1 on L0's ks loop: stops the scheduler hoisting all
//      4 ks iterations' x float4 loads (32 regs -> 8). A-offsets become
//      runtime address arithmetic (legal; L0 never indexes Hx). L1/L2 ks
//      loops STAY fully unrolled (Hx indexing m=ks>>1 must be compile-time,
//      rule #20).
//  (2) L2 bias fragments read from LDS inside the mt loop (2 ds_read_b128
//      per mt) instead of 8 persistent VGPRs.
// Core live peak now ~116 (acc 64 + Hx 32 + temps) < 128 -> spill-free at
// 2 blocks/CU x 4 waves/SIMD.
//
// Design (validated R18/R19): mfma_f32_32x32x16_bf16; token col = lane&31
// in both C and B layouts -> inter-layer h hand-off is a 2-lane exchange
// (shfl_xor 32 + cndmask), SH deleted; W2 zero-padded to 32 rows; C/D
// row=(reg&3)+8*(reg>>2)+4*(lane>>5) [m74/m101]. No in-loop barriers.
// Block = one o x 1024 tokens (8 waves x 4 mt x 32 tok); grid 512;
// XCD swizzle bid = q*128 + o*8 + c (q=0..3).
#define NTOK  32768
#define CIN   64
#define HDIM  128
#define O_CH  16
#define F2    16
#define MT    4
#define SLOPE 0.01f
#define EPS   1e-5f

// LDS layout (shorts). Weight rows 16B-aligned.
#define SW0_STRIDE 72
#define SW1_STRIDE 136
#define SW2_STRIDE 136
#define SW0_OFF 0                         // 128 x 72  = 9216
#define SW1_OFF 9216                      // 128 x 136 = 17408
#define SW2_OFF (9216 + 17408)            // 32  x 136 = 4352 (rows 16+ zero)
#define SBIAS_OFF (SW2_OFF + 32 * SW2_STRIDE)       // 30976; 4B-aligned
#define SBIAS_FLOATS 272                  // b0'(128) b1'(128) b2'(16)
#define SGB_OFF (SBIAS_OFF + SBIAS_FLOATS * 2)      // 31520
#define SGB_FLOATS 512                    // g0,be0,g1,be1
#define SMEM_SHORTS (SGB_OFF + SGB_FLOATS * 2)      // 32544 sh = 65088 B

typedef __attribute__((ext_vector_type(8)))  short bf16x8;
typedef __attribute__((ext_vector_type(4)))  float f32x4;
typedef __attribute__((ext_vector_type(16))) float f32x16;
typedef __attribute__((ext_vector_type(2)))  float f32x2;

__device__ __forceinline__ unsigned short f2b(float f) {
  union { float f; unsigned int i; } v;
  v.f = f;
  unsigned int i = v.i;
  unsigned int r = (i + 0x7fffu + ((i >> 16) & 1u)) >> 16;  // RNE
  return (unsigned short)r;
}
// native float->bf16 (RNE). [validated R10/R12/R13]
__device__ __forceinline__ unsigned short f2bn(float f) {
  union { __hip_bfloat16 h; unsigned short s; } v;
  v.h = __float2bfloat16(f);
  return v.s;
}
__device__ __forceinline__ unsigned pku(float lo, float hi) {
  return (unsigned)f2bn(lo) | ((unsigned)f2bn(hi) << 16);
}
__device__ __forceinline__ float leaky(float t) {
  return fmaxf(t, SLOPE * t);   // == LeakyReLU for all finite t
}
__device__ __forceinline__ f32x2 leaky2(f32x2 t) {
#if __has_builtin(__builtin_elementwise_max) && __has_builtin(__builtin_elementwise_min)
  f32x2 z = {0.f, 0.f};
  f32x2 pos = __builtin_elementwise_max(t, z);
  f32x2 neg = __builtin_elementwise_min(t, z);
  return pos + SLOPE * neg;
#else
  f32x2 r;
  r.x = fmaxf(t.x, SLOPE * t.x);
  r.y = fmaxf(t.y, SLOPE * t.y);
  return r;
#endif
}
__device__ __forceinline__ bf16x8 cvt8(const float* __restrict__ p) {
  float4 a = *(const float4*)p;
  float4 b = *(const float4*)(p + 4);
  bf16x8 r;
  r[0] = (short)f2b(a.x); r[1] = (short)f2b(a.y);
  r[2] = (short)f2b(a.z); r[3] = (short)f2b(a.w);
  r[4] = (short)f2b(b.x); r[5] = (short)f2b(b.y);
  r[6] = (short)f2b(b.z); r[7] = (short)f2b(b.w);
  return r;
}
__device__ __forceinline__ bf16x8 cvt8s(const float* __restrict__ p,
                                        const float* __restrict__ s) {
  bf16x8 r;
#pragma unroll
  for (int i = 0; i < 8; ++i) r[i] = (short)f2b(p[i] * s[i]);
  return r;
}

// Hand-off state: packed bf16 pairs of the lane's normalized h-values,
// pre-selected (compile-time indices only) for local/send use per ks parity.
struct Hx {
  unsigned Le01[4], Le23[4], Lo01[4], Lo23[4];
  unsigned Se01[4], Se23[4], So01[4], So23[4];
};

// leaky + LayerNorm on 32x32 C-layout. Lane (t=l&31,u=l>>5) holds
// h = 32m+8g+4u+i (m,g=0..3,i=0..3) of token t; lane pair (l,l^32) holds
// all 128. Stats: in-lane 64-sum (f32x2 chains) + ONE shfl_xor(32).
// Pack p01/p23[g] per m, then u-select into Le/Lo (local g=u,2+u) and
// Se/So (send g=1-u,3-u).  [validated R18/R19]
__device__ __forceinline__ void leaky_ln_hand(f32x16* acc, int u, Hx& h) {
  f32x2 sa = {0.f, 0.f}, sb = {0.f, 0.f};
  f32x2 qa = {0.f, 0.f}, qb = {0.f, 0.f};
#pragma unroll
  for (int m = 0; m < 4; ++m) {
#pragma unroll
    for (int g = 0; g < 4; ++g) {
      f32x2 t0 = {acc[m][4 * g + 0], acc[m][4 * g + 1]};
      f32x2 t1 = {acc[m][4 * g + 2], acc[m][4 * g + 3]};
      t0 = leaky2(t0);
      t1 = leaky2(t1);
      acc[m][4 * g + 0] = t0.x; acc[m][4 * g + 1] = t0.y;
      acc[m][4 * g + 2] = t1.x; acc[m][4 * g + 3] = t1.y;
      sa += t0; sb += t1;
      qa += t0 * t0; qb += t1 * t1;
    }
  }
  float s1 = (sa.x + sa.y) + (sb.x + sb.y);
  float s2 = (qa.x + qa.y) + (qb.x + qb.y);
  s1 += __shfl_xor(s1, 32);
  s2 += __shfl_xor(s2, 32);
  float mu = s1 * (1.0f / 128.0f);
  float var = s2 * (1.0f / 128.0f) - mu * mu;
  float rs = rsqrtf(var + EPS);
  float nm = -mu * rs;
#pragma unroll
  for (int m = 0; m < 4; ++m) {
    unsigned p01[4], p23[4];
#pragma unroll
    for (int g = 0; g < 4; ++g) {
      float y0 = fmaf(acc[m][4 * g + 0], rs, nm);
      float y1 = fmaf(acc[m][4 * g + 1], rs, nm);
      float y2 = fmaf(acc[m][4 * g + 2], rs, nm);
      float y3 = fmaf(acc[m][4 * g + 3], rs, nm);
      p01[g] = pku(y0, y1);
      p23[g] = pku(y2, y3);
    }
    h.Le01[m] = u ? p01[1] : p01[0];  h.Le23[m] = u ? p23[1] : p23[0];
    h.Lo01[m] = u ? p01[3] : p01[2];  h.Lo23[m] = u ? p23[3] : p23[2];
    h.Se01[m] = u ? p01[0] : p01[1];  h.Se23[m] = u ? p23[0] : p23[1];
    h.So01[m] = u ? p01[2] : p01[3];  h.So23[m] = u ? p23[2] : p23[3];
  }
}

// B-fragment for k-step ks (K=16 each): words 0,1 from the u'=0 owner
// (lane t), words 2,3 from u'=1 (lane t+32). ks compile-time via unroll.
// [validated R18/R19]
__device__ __forceinline__ bf16x8 build_b(const Hx& h, int ks, int u) {
  const int m = ks >> 1;
  unsigned sA, sB, lA, lB;
  if (ks & 1) { sA = h.So01[m]; sB = h.So23[m]; lA = h.Lo01[m]; lB = h.Lo23[m]; }
  else        { sA = h.Se01[m]; sB = h.Se23[m]; lA = h.Le01[m]; lB = h.Le23[m]; }
  unsigned rA = __shfl_xor(sA, 32);
  unsigned rB = __shfl_xor(sB, 32);
  union { unsigned w[4]; bf16x8 v; } b;
  b.w[0] = u ? rA : lA;  b.w[1] = u ? rB : lB;
  b.w[2] = u ? lA : rA;  b.w[3] = u ? lB : rB;
  return b.v;
}

// film_main: 512-thread block = one o x 1024 tokens (8 waves x 4 mt x 32).
// LDS 65.1KB -> 2 blocks/CU; demand < 128 VGPR -> spill-free at
// 4 waves/SIMD. No in-loop barriers (no shared scratch).
__global__ __launch_bounds__(512) void film_main(
    const float* __restrict__ x,
    const float* __restrict__ W0, const float* __restrict__ b0,
    const float* __restrict__ g0, const float* __restrict__ be0,
    const float* __restrict__ W1, const float* __restrict__ b1,
    const float* __restrict__ g1, const float* __restrict__ be1,
    const float* __restrict__ W2, const float* __restrict__ b2,
    float* __restrict__ out) {
  __shared__ unsigned short smem[SMEM_SHORTS];
  const int tid = threadIdx.x;
  const int c   = blockIdx.x & 7;
  const int o   = (blockIdx.x >> 3) & 15;
  const int q   = blockIdx.x >> 7;              // 0..3
  const int tok0 = (q * 8 + c) * 1024;

  float* sbias = (float*)&smem[SBIAS_OFF];
  float* sgb   = (float*)&smem[SGB_OFF];
  float* sg0v  = sgb;
  float* sbe0v = sgb + 128;
  float* sg1v  = sgb + 256;
  float* sbe1v = sgb + 384;

  // ---- staging 1: gamma/beta fp32 into LDS (512 threads cover 512 vals)
  if (tid < 128)      sg0v [tid]       = g0 [o * HDIM + tid];
  else if (tid < 256) sbe0v[tid - 128] = be0[o * HDIM + (tid - 128)];
  else if (tid < 384) sg1v [tid - 256] = g1 [o * HDIM + (tid - 256)];
  else                sbe1v[tid - 384] = be1[o * HDIM + (tid - 384)];
  __syncthreads();

  // ---- staging 2: weight image + folded biases (512-thread striding)
  const float* w0 = W0 + (size_t)o * HDIM * CIN;
  const float* w1 = W1 + (size_t)o * HDIM * HDIM;
  const float* w2 = W2 + (size_t)o * F2 * HDIM;
#pragma unroll
  for (int rep = 0; rep < 2; ++rep) {  // W0: 1024 chunks of 8
    int cc = tid + rep * 512, n = cc >> 3, k8 = cc & 7;
    *(bf16x8*)&smem[SW0_OFF + n * SW0_STRIDE + k8 * 8] = cvt8(w0 + cc * 8);
  }
#pragma unroll
  for (int rep = 0; rep < 4; ++rep) {  // W1: 2048 chunks
    int cc = tid + rep * 512, n = cc >> 4, k8 = cc & 15;
    *(bf16x8*)&smem[SW1_OFF + n * SW1_STRIDE + k8 * 8] =
        cvt8s(w1 + cc * 8, sg0v + k8 * 8);         // W1' = W1 * g0[k]
  }
  {  // W2 padded to 32 rows: rows 16..31 zero (512 chunks, one each)
    int cc = tid, n = cc >> 4, k8 = cc & 15;
    bf16x8 v;
    if (n < 16) {
      v = cvt8s(w2 + (n * HDIM + k8 * 8), sg1v + k8 * 8);  // W2' = W2 * g1
    } else {
#pragma unroll
      for (int i = 0; i < 8; ++i) v[i] = 0;
    }
    *(bf16x8*)&smem[SW2_OFF + n * SW2_STRIDE + k8 * 8] = v;
  }
  if (tid < 128) sbias[tid] = b0[o * HDIM + tid];  // b0' = b0
  {  // b1' = b1 + W1*be0 : 4 threads per h-row, 32-elem partials + reduce
    int hrow = tid >> 2, seg = tid & 3;
    const float* w1r = w1 + (size_t)hrow * HDIM + seg * 32;
    const float* bev = sbe0v + seg * 32;
    float p = 0.f;
#pragma unroll
    for (int k = 0; k < 32; ++k) p = fmaf(w1r[k], bev[k], p);
    p += __shfl_xor(p, 1); p += __shfl_xor(p, 2);
    if (seg == 0) sbias[HDIM + hrow] = b1[o * HDIM + hrow] + p;
  }
  if (tid < 128) {  // b2' = b2 + W2*be1 : 8 threads per f-row
    int f = tid >> 3, seg = tid & 7;
    const float* w2r = w2 + (size_t)f * HDIM + seg * 16;
    const float* bev = sbe1v + seg * 16;
    float p = 0.f;
#pragma unroll
    for (int k = 0; k < 16; ++k) p = fmaf(w2r[k], bev[k], p);
    p += __shfl_xor(p, 1); p += __shfl_xor(p, 2); p += __shfl_xor(p, 4);
    if (seg == 0) sbias[2 * HDIM + f] = b2[o * F2 + f] + p;
  }

  const int lane = tid & 63;
  const int wave = tid >> 6;        // 0..7
  const int t32  = lane & 31;       // token column (C and B layouts)
  const int u    = lane >> 5;       // lane-half
  const float* sb0 = sbias;
  const float* sb1 = sbias + HDIM;
  const float* sb2 = sbias + 2 * HDIM;
  __syncthreads();

  // hoisted LDS byte bases (A-reads: row = t32 (+32m), k-offset 8u)
  const unsigned short* a0p = &smem[SW0_OFF + t32 * SW0_STRIDE + 8 * u];
  const unsigned short* a1p = &smem[SW1_OFF + t32 * SW1_STRIDE + 8 * u];
  const unsigned short* a2p = &smem[SW2_OFF + t32 * SW2_STRIDE + 8 * u];

  const int tbase = tok0 + wave * (32 * MT);

  for (int mt = 0; mt < MT; ++mt) {
    const int trow = tbase + mt * 32;
    const float* xr = x + (size_t)(trow + t32) * CIN + 8 * u;

    // ---- Layer 0: A=W0 (LDS), B=x (global, fp32 -> bf16 native cvt).
    // unroll 1: keeps only ONE ks iteration's x-regs live (8 floats, not
    // 32) -- the R19 spill source. A-offsets are runtime addr arithmetic.
    f32x16 acc[4];
#pragma unroll
    for (int m = 0; m < 4; ++m)
#pragma unroll
      for (int g = 0; g < 4; ++g) {
        f32x4 bv = *(const f32x4*)(sb0 + 32 * m + 8 * g + 4 * u);
#pragma unroll
        for (int i = 0; i < 4; ++i) acc[m][4 * g + i] = bv[i];
      }
#pragma unroll 1
    for (int ks = 0; ks < 4; ++ks) {
      float4 xa = *(const float4*)(xr + 16 * ks);
      float4 xb = *(const float4*)(xr + 16 * ks + 4);
      bf16x8 bx;
      bx[0] = (short)f2bn(xa.x); bx[1] = (short)f2bn(xa.y);
      bx[2] = (short)f2bn(xa.z); bx[3] = (short)f2bn(xa.w);
      bx[4] = (short)f2bn(xb.x); bx[5] = (short)f2bn(xb.y);
      bx[6] = (short)f2bn(xb.z); bx[7] = (short)f2bn(xb.w);
#pragma unroll
      for (int m = 0; m < 4; ++m) {
        bf16x8 a = *(const bf16x8*)(a0p + m * 32 * SW0_STRIDE + 16 * ks);
        acc[m] = __builtin_amdgcn_mfma_f32_32x32x16_bf16(a, bx, acc[m], 0, 0, 0);
      }
    }
    Hx hx;
    leaky_ln_hand(acc, u, hx);

    // ---- Layer 1: A=W1' (LDS), B=h0 via 2-lane register exchange.
    // MUST stay fully unrolled: Hx indexing (m=ks>>1) is compile-time.
#pragma unroll
    for (int m = 0; m < 4; ++m)
#pragma unroll
      for (int g = 0; g < 4; ++g) {
        f32x4 bv = *(const f32x4*)(sb1 + 32 * m + 8 * g + 4 * u);
#pragma unroll
        for (int i = 0; i < 4; ++i) acc[m][4 * g + i] = bv[i];
      }
#pragma unroll
    for (int ks = 0; ks < 8; ++ks) {
      bf16x8 bh = build_b(hx, ks, u);
#pragma unroll
      for (int m = 0; m < 4; ++m) {
        bf16x8 a = *(const bf16x8*)(a1p + m * 32 * SW1_STRIDE + 16 * ks);
        acc[m] = __builtin_amdgcn_mfma_f32_32x32x16_bf16(a, bh, acc[m], 0, 0, 0);
      }
    }
    leaky_ln_hand(acc, u, hx);

    // ---- Layer 2: A=W2' (32-row zero-padded), B=h1. Bias from LDS here
    // (not persistent regs): f = 4u + (reg&3) + 8*(reg>>2), regs 0..7.
    f32x16 acc2;
    {
      const f32x4 bra = *(const f32x4*)(sb2 + 4 * u);      // regs 0..3
      const f32x4 brb = *(const f32x4*)(sb2 + 8 + 4 * u);  // regs 4..7
#pragma unroll
      for (int i = 0; i < 4; ++i) acc2[i] = bra[i];
#pragma unroll
      for (int i = 0; i < 4; ++i) acc2[4 + i] = brb[i];
#pragma unroll
      for (int i = 8; i < 16; ++i) acc2[i] = 0.f;
    }
#pragma unroll
    for (int ks = 0; ks < 8; ++ks) {
      bf16x8 bh = build_b(hx, ks, u);
      bf16x8 a = *(const bf16x8*)(a2p + 16 * ks);
      acc2 = __builtin_amdgcn_mfma_f32_32x32x16_bf16(a, bh, acc2, 0, 0, 0);
    }
    // out[tok][f][o]: f = 4u + (reg&3) + 8*(reg>>2), regs 0..7 only.
    {
      float* ob = out + (size_t)(trow + t32) * (F2 * O_CH) + 64 * u + o;
#pragma unroll
      for (int r = 0; r < 4; ++r) ob[16 * r]       = leaky(acc2[r]);
#pragma unroll
      for (int r = 0; r < 4; ++r) ob[16 * (8 + r)] = leaky(acc2[4 + r]);
    }
  }
}

extern "C" void kernel_launch(void* const* d_in, const int* in_sizes, int n_in,
                              void* d_out, int out_size, void* d_ws, size_t ws_size,
                              hipStream_t stream) {
  (void)in_sizes; (void)n_in; (void)out_size; (void)d_ws; (void)ws_size;
  const float* x   = (const float*)d_in[0];
  const float* W0  = (const float*)d_in[1];
  const float* b0  = (const float*)d_in[2];
  const float* g0  = (const float*)d_in[3];
  const float* be0 = (const float*)d_in[4];
  const float* W1  = (const float*)d_in[5];
  const float* b1  = (const float*)d_in[6];
  const float* g1  = (const float*)d_in[7];
  const float* be1 = (const float*)d_in[8];
  const float* W2  = (const float*)d_in[9];
  const float* b2  = (const float*)d_in[10];

  // 512 blocks: 16 o-channels x 32 token-groups of 1024.
  film_main<<<dim3(O_CH * (NTOK / 1024)), dim3(512), 0, stream>>>(
      x, W0, b0, g0, be0, W1, b1, g1, be1, W2, b2, (float*)d_out);
}